// Round 6
// baseline (513.421 us; speedup 1.0000x reference)
//
#include <hip/hip_runtime.h>
#include <math.h>

#define NUM_TREES 20000
#define MAX_DEPTH 8
#define MAX_SIZE  40
#define VOCAB     30000
#define DIM       128
#define TOT       (MAX_DEPTH * MAX_SIZE)   // 320 tokens per tree

__device__ __forceinline__ double waveSumD(double v) {
    v += __shfl_xor(v, 32);
    v += __shfl_xor(v, 16);
    v += __shfl_xor(v, 8);
    v += __shfl_xor(v, 4);
    v += __shfl_xor(v, 2);
    v += __shfl_xor(v, 1);
    return v;
}
__device__ __forceinline__ double waveMaxD(double v) {
    v = fmax(v, __shfl_xor(v, 32));
    v = fmax(v, __shfl_xor(v, 16));
    v = fmax(v, __shfl_xor(v, 8));
    v = fmax(v, __shfl_xor(v, 4));
    v = fmax(v, __shfl_xor(v, 2));
    v = fmax(v, __shfl_xor(v, 1));
    return v;
}

// masks may arrive as 1-byte bool or int32; probe word 0 (all-ones input:
// byte layout reads 0x01010101, int32 layout reads 0x00000001).
__device__ __forceinline__ int loadMask(const void* m, size_t idx, bool asByte) {
    return asByte ? (int)((const unsigned char*)m)[idx] : ((const int*)m)[idx];
}

// ---------------------------------------------------------------------------
// Phase 0: ts[v] = dot(embedding[v], context_weight) in fp64.
// 4 rows per wave (4 independent loads in flight -> latency hidden by ILP).
__global__ __launch_bounds__(256) void tokscore_kernel(
        const float* __restrict__ emb, const float* __restrict__ cw,
        double* __restrict__ ts) {
    const int wid  = (blockIdx.x * blockDim.x + threadIdx.x) >> 6;  // wave id
    const int lane = threadIdx.x & 63;
    const int r0   = wid * 4;
    if (r0 >= VOCAB) return;
    const float2 w2 = *(const float2*)(cw + lane * 2);
    const float* e  = emb + (size_t)r0 * DIM + lane * 2;
    const float2 x0 = *(const float2*)(e);
    const float2 x1 = *(const float2*)(e + DIM);
    const float2 x2 = *(const float2*)(e + 2 * DIM);
    const float2 x3 = *(const float2*)(e + 3 * DIM);
    double p0 = (double)x0.x * (double)w2.x + (double)x0.y * (double)w2.y;
    double p1 = (double)x1.x * (double)w2.x + (double)x1.y * (double)w2.y;
    double p2 = (double)x2.x * (double)w2.x + (double)x2.y * (double)w2.y;
    double p3 = (double)x3.x * (double)w2.x + (double)x3.y * (double)w2.y;
    #pragma unroll
    for (int off = 32; off; off >>= 1) {
        p0 += __shfl_xor(p0, off);
        p1 += __shfl_xor(p1, off);
        p2 += __shfl_xor(p2, off);
        p3 += __shfl_xor(p3, off);
    }
    if (lane == 0) {
        ts[r0]     = p0;
        ts[r0 + 1] = p1;
        ts[r0 + 2] = p2;
        ts[r0 + 3] = p3;
    }
}

// ---------------------------------------------------------------------------
// Phase 1: per-tree fp64 scalar recursion -> 320 fp32 coefficients.
// One wave per tree, all state in registers (no LDS). Math is operation-for-
// operation identical to the round-4 kernel that passed (incl. final
// float(attn_d * prefix_d) rounding).
__global__ __launch_bounds__(256) void coef_kernel(
        const int* __restrict__ tokens, const void* __restrict__ masks,
        const double* __restrict__ ts, float* __restrict__ coef) {
    const int wid  = blockIdx.x * 4 + (threadIdx.x >> 6);   // tree id
    const int lane = threadIdx.x & 63;
    if (wid >= NUM_TREES) return;
    const size_t base = (size_t)wid * TOT;
    const bool mByte = (((const int*)masks)[0] != 1);
    const bool inS = lane < MAX_SIZE;

    int tokA[MAX_DEPTH]; int mskA[MAX_DEPTH]; int valA[MAX_DEPTH];
    double eA[MAX_DEPTH];
    #pragma unroll
    for (int d = 0; d < MAX_DEPTH; ++d) {
        const int idx = d * MAX_SIZE + lane;
        int t = inS ? tokens[base + idx] : -1;
        int m = inS ? loadMask(masks, base + idx, mByte) : 0;
        tokA[d] = t < 0 ? 0 : t;
        mskA[d] = (m != 0);
        valA[d] = (m != 0) && (t >= 0);
        eA[d]   = ts[tokA[d]];
    }

    double pw = waveSumD((inS && valA[7]) ? eA[7] : 0.0);

    double attnA[MAX_DEPTH - 1];
    double cArr[MAX_DEPTH - 1];
    #pragma unroll
    for (int d = MAX_DEPTH - 2; d >= 0; --d) {
        double e     = inS ? eA[d] : 0.0;
        double vd    = (inS && valA[d]) ? 1.0 : 0.0;
        double mnext = (inS && mskA[d + 1]) ? 1.0 : 0.0;
        double ncf   = fmax(waveSumD(mnext), 1.0);          // child count
        double child = (vd > 0.0 && (double)lane < ncf) ? 1.0 : 0.0;
        double gate  = 1.0 / (1.0 + exp(-e));
        double a     = e + gate * child * pw;
        double am    = vd > 0.0 ? a : -__builtin_inf();
        double mx    = waveMaxD(am);
        double ex    = vd > 0.0 ? exp(a - mx) : 0.0;
        double den   = waveSumD(ex);
        double attn  = ex / den;
        double c     = waveSumD(attn * gate * child);
        pw = waveSumD(attn * e) + c * pw;
        attnA[d] = attn;
        cArr[d]  = c;
    }

    float cf[MAX_DEPTH];
    double prefix = 1.0;
    #pragma unroll
    for (int d = 0; d < MAX_DEPTH - 1; ++d) {
        cf[d] = (float)(attnA[d] * prefix);
        prefix *= cArr[d];
    }
    cf[7] = (float)(prefix * ((inS && valA[7]) ? 1.0 : 0.0));

    if (inS) {
        #pragma unroll
        for (int d = 0; d < MAX_DEPTH; ++d)
            coef[base + d * MAX_SIZE + lane] = cf[d];
    }
}

// ---------------------------------------------------------------------------
// Phase 2: pure gather-FMA. out[tree] = sum_i coef[i] * emb[tok[i]].
// One block per tree; 8 groups of 32 lanes; group g owns rows i = g + 8*j.
// Software-pipelined batches of 8 row-loads, fully unrolled (40 straight-line
// loads). amdgpu_waves_per_eu(2,2) hard-targets 2 waves/EU so the register
// allocator is free to keep many float4 loads in flight (R4/R5 showed the
// default occupancy target pins VGPR=36 and serializes the loads).
__global__ __attribute__((amdgpu_flat_work_group_size(256, 256),
                          amdgpu_waves_per_eu(2, 2)))
void gather_kernel(const int* __restrict__ tokens,
                   const float* __restrict__ coef,
                   const float* __restrict__ emb,
                   float* __restrict__ out) {
    __shared__ int   s_tok[TOT];
    __shared__ float s_cf[TOT];
    __shared__ float s_red[8][DIM];

    const int tree = blockIdx.x;
    const int tid  = threadIdx.x;
    const size_t base = (size_t)tree * TOT;

    for (int i = tid; i < TOT; i += 256) {
        int t = tokens[base + i];
        s_tok[i] = t < 0 ? 0 : t;
        s_cf[i]  = coef[base + i];
    }
    __syncthreads();

    const int grp = tid >> 5;
    const int col = (tid & 31) << 2;
    const float* ebase = emb + col;

    float4 a0 = {0,0,0,0}, a1 = {0,0,0,0}, a2 = {0,0,0,0}, a3 = {0,0,0,0};

    float4 cur[8]; float cc[8];
    #pragma unroll
    for (int k = 0; k < 8; ++k) {
        const int i = grp + 8 * k;
        cc[k]  = s_cf[i];
        cur[k] = *(const float4*)(ebase + ((size_t)s_tok[i] << 7));
    }
    #pragma unroll
    for (int b = 1; b <= 4; ++b) {
        float4 nxt[8]; float nc[8];
        #pragma unroll
        for (int k = 0; k < 8; ++k) {
            const int i = grp + 8 * (8 * b + k);
            nc[k]  = s_cf[i];
            nxt[k] = *(const float4*)(ebase + ((size_t)s_tok[i] << 7));
        }
        a0.x = fmaf(cc[0], cur[0].x, a0.x); a0.y = fmaf(cc[0], cur[0].y, a0.y);
        a0.z = fmaf(cc[0], cur[0].z, a0.z); a0.w = fmaf(cc[0], cur[0].w, a0.w);
        a1.x = fmaf(cc[1], cur[1].x, a1.x); a1.y = fmaf(cc[1], cur[1].y, a1.y);
        a1.z = fmaf(cc[1], cur[1].z, a1.z); a1.w = fmaf(cc[1], cur[1].w, a1.w);
        a2.x = fmaf(cc[2], cur[2].x, a2.x); a2.y = fmaf(cc[2], cur[2].y, a2.y);
        a2.z = fmaf(cc[2], cur[2].z, a2.z); a2.w = fmaf(cc[2], cur[2].w, a2.w);
        a3.x = fmaf(cc[3], cur[3].x, a3.x); a3.y = fmaf(cc[3], cur[3].y, a3.y);
        a3.z = fmaf(cc[3], cur[3].z, a3.z); a3.w = fmaf(cc[3], cur[3].w, a3.w);
        a0.x = fmaf(cc[4], cur[4].x, a0.x); a0.y = fmaf(cc[4], cur[4].y, a0.y);
        a0.z = fmaf(cc[4], cur[4].z, a0.z); a0.w = fmaf(cc[4], cur[4].w, a0.w);
        a1.x = fmaf(cc[5], cur[5].x, a1.x); a1.y = fmaf(cc[5], cur[5].y, a1.y);
        a1.z = fmaf(cc[5], cur[5].z, a1.z); a1.w = fmaf(cc[5], cur[5].w, a1.w);
        a2.x = fmaf(cc[6], cur[6].x, a2.x); a2.y = fmaf(cc[6], cur[6].y, a2.y);
        a2.z = fmaf(cc[6], cur[6].z, a2.z); a2.w = fmaf(cc[6], cur[6].w, a2.w);
        a3.x = fmaf(cc[7], cur[7].x, a3.x); a3.y = fmaf(cc[7], cur[7].y, a3.y);
        a3.z = fmaf(cc[7], cur[7].z, a3.z); a3.w = fmaf(cc[7], cur[7].w, a3.w);
        #pragma unroll
        for (int k = 0; k < 8; ++k) { cur[k] = nxt[k]; cc[k] = nc[k]; }
    }
    a0.x = fmaf(cc[0], cur[0].x, a0.x); a0.y = fmaf(cc[0], cur[0].y, a0.y);
    a0.z = fmaf(cc[0], cur[0].z, a0.z); a0.w = fmaf(cc[0], cur[0].w, a0.w);
    a1.x = fmaf(cc[1], cur[1].x, a1.x); a1.y = fmaf(cc[1], cur[1].y, a1.y);
    a1.z = fmaf(cc[1], cur[1].z, a1.z); a1.w = fmaf(cc[1], cur[1].w, a1.w);
    a2.x = fmaf(cc[2], cur[2].x, a2.x); a2.y = fmaf(cc[2], cur[2].y, a2.y);
    a2.z = fmaf(cc[2], cur[2].z, a2.z); a2.w = fmaf(cc[2], cur[2].w, a2.w);
    a3.x = fmaf(cc[3], cur[3].x, a3.x); a3.y = fmaf(cc[3], cur[3].y, a3.y);
    a3.z = fmaf(cc[3], cur[3].z, a3.z); a3.w = fmaf(cc[3], cur[3].w, a3.w);
    a0.x = fmaf(cc[4], cur[4].x, a0.x); a0.y = fmaf(cc[4], cur[4].y, a0.y);
    a0.z = fmaf(cc[4], cur[4].z, a0.z); a0.w = fmaf(cc[4], cur[4].w, a0.w);
    a1.x = fmaf(cc[5], cur[5].x, a1.x); a1.y = fmaf(cc[5], cur[5].y, a1.y);
    a1.z = fmaf(cc[5], cur[5].z, a1.z); a1.w = fmaf(cc[5], cur[5].w, a1.w);
    a2.x = fmaf(cc[6], cur[6].x, a2.x); a2.y = fmaf(cc[6], cur[6].y, a2.y);
    a2.z = fmaf(cc[6], cur[6].z, a2.z); a2.w = fmaf(cc[6], cur[6].w, a2.w);
    a3.x = fmaf(cc[7], cur[7].x, a3.x); a3.y = fmaf(cc[7], cur[7].y, a3.y);
    a3.z = fmaf(cc[7], cur[7].z, a3.z); a3.w = fmaf(cc[7], cur[7].w, a3.w);

    float4 acc;
    acc.x = (a0.x + a1.x) + (a2.x + a3.x);
    acc.y = (a0.y + a1.y) + (a2.y + a3.y);
    acc.z = (a0.z + a1.z) + (a2.z + a3.z);
    acc.w = (a0.w + a1.w) + (a2.w + a3.w);
    *(float4*)(&s_red[grp][col]) = acc;
    __syncthreads();
    if (tid < DIM) {
        float r = 0.f;
        #pragma unroll
        for (int g = 0; g < 8; ++g) r += s_red[g][tid];
        out[(size_t)tree * DIM + tid] = r;
    }
}

// ---------------------------------------------------------------------------
// Fallback: round-4 fused kernel (passed all checks) if ws is too small for
// the coef buffer.
__global__ __launch_bounds__(256) void encode_fused_kernel(
        const int* __restrict__ tokens, const void* __restrict__ masks,
        const float* __restrict__ emb, const double* __restrict__ ts,
        float* __restrict__ out) {
    __shared__ int           s_tok[TOT];
    __shared__ double        s_e[TOT];
    __shared__ unsigned char s_val[TOT];
    __shared__ unsigned char s_msk[TOT];
    __shared__ double        s_coef[TOT];
    __shared__ float         s_red[8][DIM];

    const int tree = blockIdx.x;
    const int tid  = threadIdx.x;
    const size_t base = (size_t)tree * TOT;
    const bool mByte = (((const int*)masks)[0] != 1);

    for (int i = tid; i < TOT; i += 256) {
        int t = tokens[base + i];
        int m = loadMask(masks, base + i, mByte);
        int tc = t < 0 ? 0 : t;
        s_tok[i] = tc;
        s_e[i]   = ts[tc];
        s_msk[i] = (unsigned char)(m != 0);
        s_val[i] = (unsigned char)((m != 0) && t >= 0);
    }
    __syncthreads();

    if (tid < 64) {
        const int s = tid;
        const bool inS = s < MAX_SIZE;
        double e7 = 0.0, v7 = 0.0;
        if (inS) {
            e7 = s_e[7 * MAX_SIZE + s];
            v7 = s_val[7 * MAX_SIZE + s] ? 1.0 : 0.0;
        }
        double pw = waveSumD(e7 * v7);
        double cArr[MAX_DEPTH - 1];
        #pragma unroll
        for (int d = MAX_DEPTH - 2; d >= 0; --d) {
            double e = 0.0, vd = 0.0, mnext = 0.0;
            if (inS) {
                e     = s_e[d * MAX_SIZE + s];
                vd    = s_val[d * MAX_SIZE + s] ? 1.0 : 0.0;
                mnext = s_msk[(d + 1) * MAX_SIZE + s] ? 1.0 : 0.0;
            }
            double ncf = fmax(waveSumD(mnext), 1.0);
            double child = (vd > 0.0 && (double)s < ncf) ? 1.0 : 0.0;
            double gate  = 1.0 / (1.0 + exp(-e));
            double a     = e + gate * child * pw;
            double am    = vd > 0.0 ? a : -__builtin_inf();
            double mx    = waveMaxD(am);
            double ex    = vd > 0.0 ? exp(a - mx) : 0.0;
            double den   = waveSumD(ex);
            double attn  = ex / den;
            double c     = waveSumD(attn * gate * child);
            pw = waveSumD(attn * e) + c * pw;
            if (inS) s_coef[d * MAX_SIZE + s] = attn;
            cArr[d] = c;
        }
        double prefix = 1.0;
        #pragma unroll
        for (int d = 0; d <= MAX_DEPTH - 2; ++d) {
            if (inS) s_coef[d * MAX_SIZE + s] *= prefix;
            prefix *= cArr[d];
        }
        if (inS) s_coef[7 * MAX_SIZE + s] = prefix * v7;
    }
    __syncthreads();

    const int grp = tid >> 5;
    const int col = (tid & 31) << 2;
    float4 a0 = {0,0,0,0}, a1 = {0,0,0,0}, a2 = {0,0,0,0}, a3 = {0,0,0,0};
    #pragma unroll 1
    for (int j = 0; j < 40; j += 8) {
        const int i0 = grp + 8 * j;
        int t0 = s_tok[i0];      int t1 = s_tok[i0 + 8];
        int t2 = s_tok[i0 + 16]; int t3 = s_tok[i0 + 24];
        int t4 = s_tok[i0 + 32]; int t5 = s_tok[i0 + 40];
        int t6 = s_tok[i0 + 48]; int t7 = s_tok[i0 + 56];
        float c0 = (float)s_coef[i0];      float c1 = (float)s_coef[i0 + 8];
        float c2 = (float)s_coef[i0 + 16]; float c3 = (float)s_coef[i0 + 24];
        float c4 = (float)s_coef[i0 + 32]; float c5 = (float)s_coef[i0 + 40];
        float c6 = (float)s_coef[i0 + 48]; float c7 = (float)s_coef[i0 + 56];
        float4 v0 = *(const float4*)(emb + (size_t)t0 * DIM + col);
        float4 v1 = *(const float4*)(emb + (size_t)t1 * DIM + col);
        float4 v2 = *(const float4*)(emb + (size_t)t2 * DIM + col);
        float4 v3 = *(const float4*)(emb + (size_t)t3 * DIM + col);
        float4 v4 = *(const float4*)(emb + (size_t)t4 * DIM + col);
        float4 v5 = *(const float4*)(emb + (size_t)t5 * DIM + col);
        float4 v6 = *(const float4*)(emb + (size_t)t6 * DIM + col);
        float4 v7 = *(const float4*)(emb + (size_t)t7 * DIM + col);
        a0.x = fmaf(c0, v0.x, a0.x); a0.y = fmaf(c0, v0.y, a0.y);
        a0.z = fmaf(c0, v0.z, a0.z); a0.w = fmaf(c0, v0.w, a0.w);
        a1.x = fmaf(c1, v1.x, a1.x); a1.y = fmaf(c1, v1.y, a1.y);
        a1.z = fmaf(c1, v1.z, a1.z); a1.w = fmaf(c1, v1.w, a1.w);
        a2.x = fmaf(c2, v2.x, a2.x); a2.y = fmaf(c2, v2.y, a2.y);
        a2.z = fmaf(c2, v2.z, a2.z); a2.w = fmaf(c2, v2.w, a2.w);
        a3.x = fmaf(c3, v3.x, a3.x); a3.y = fmaf(c3, v3.y, a3.y);
        a3.z = fmaf(c3, v3.z, a3.z); a3.w = fmaf(c3, v3.w, a3.w);
        a0.x = fmaf(c4, v4.x, a0.x); a0.y = fmaf(c4, v4.y, a0.y);
        a0.z = fmaf(c4, v4.z, a0.z); a0.w = fmaf(c4, v4.w, a0.w);
        a1.x = fmaf(c5, v5.x, a1.x); a1.y = fmaf(c5, v5.y, a1.y);
        a1.z = fmaf(c5, v5.z, a1.z); a1.w = fmaf(c5, v5.w, a1.w);
        a2.x = fmaf(c6, v6.x, a2.x); a2.y = fmaf(c6, v6.y, a2.y);
        a2.z = fmaf(c6, v6.z, a2.z); a2.w = fmaf(c6, v6.w, a2.w);
        a3.x = fmaf(c7, v7.x, a3.x); a3.y = fmaf(c7, v7.y, a3.y);
        a3.z = fmaf(c7, v7.z, a3.z); a3.w = fmaf(c7, v7.w, a3.w);
    }
    float4 acc;
    acc.x = (a0.x + a1.x) + (a2.x + a3.x);
    acc.y = (a0.y + a1.y) + (a2.y + a3.y);
    acc.z = (a0.z + a1.z) + (a2.z + a3.z);
    acc.w = (a0.w + a1.w) + (a2.w + a3.w);
    *(float4*)(&s_red[grp][col]) = acc;
    __syncthreads();
    if (tid < DIM) {
        float r = 0.f;
        #pragma unroll
        for (int g = 0; g < 8; ++g) r += s_red[g][tid];
        out[(size_t)tree * DIM + tid] = r;
    }
}

extern "C" void kernel_launch(void* const* d_in, const int* in_sizes, int n_in,
                              void* d_out, int out_size, void* d_ws, size_t ws_size,
                              hipStream_t stream) {
    const int*   tokens = (const int*)d_in[0];
    const void*  masks  = d_in[1];
    const float* emb    = (const float*)d_in[2];
    const float* cw     = (const float*)d_in[3];
    float*       out    = (float*)d_out;

    double* ts   = (double*)d_ws;                              // 240 KB
    float*  coef = (float*)((char*)d_ws + 240 * 1024);         // 25.6 MB
    const size_t need = 240 * 1024 + (size_t)NUM_TREES * TOT * sizeof(float);

    tokscore_kernel<<<(VOCAB / 4) * 64 / 256, 256, 0, stream>>>(emb, cw, ts);

    if (ws_size >= need) {
        coef_kernel<<<NUM_TREES / 4, 256, 0, stream>>>(tokens, masks, ts, coef);
        gather_kernel<<<NUM_TREES, 256, 0, stream>>>(tokens, coef, emb, out);
    } else {
        encode_fused_kernel<<<NUM_TREES, 256, 0, stream>>>(tokens, masks, emb, ts, out);
    }
}